// Round 1
// baseline (4190.502 us; speedup 1.0000x reference)
//
#include <hip/hip_runtime.h>
#include <stdint.h>

namespace {

constexpr int B_ = 2, T_ = 2048, C_ = 2048, H_ = 16, D_ = 128;
constexpr int R_ = B_ * T_;                 // 4096 token rows (b*T + t)
constexpr float EPSF = 1e-5f;
constexpr float INV_SQRT_D = 0.08838834764831845f;   // 1/sqrt(128)

// ---- workspace layout (bytes) ----
constexpr size_t OFF_WSUM = 0;                                   // double[4]
constexpr size_t OFF_SW   = 64;                                  // float[4]
constexpr size_t OFF_WT   = 256;                                 // int8[4][C*C] ternary
constexpr size_t OFF_XQ   = OFF_WT   + (size_t)4 * C_ * C_;      // int8[R*C]
constexpr size_t OFF_SX   = OFF_XQ   + (size_t)R_ * C_;          // float[R]
constexpr size_t OFF_QKV  = OFF_SX   + (size_t)R_ * 4;           // int8[3][B*H*T*D]
constexpr size_t OFF_SQKV = OFF_QKV  + (size_t)3 * R_ * C_;      // float[3][B*H*T]
constexpr size_t OFF_YQ   = OFF_SQKV + (size_t)3 * R_ * H_ * 4;  // int8[R*C]  ([b*T+t][h*D+d])
constexpr size_t OFF_SY   = OFF_YQ   + (size_t)R_ * C_;          // float[R*H] ([b*T+t][h])
constexpr size_t OFF_OUTP = OFF_SY   + (size_t)R_ * H_ * 4;      // float[R*C]
// total ~89 MB

__device__ __forceinline__ int dot4i8(uint32_t a, uint32_t b) {
  return (int)(int8_t)(a      ) * (int)(int8_t)(b      )
       + (int)(int8_t)(a >>  8) * (int)(int8_t)(b >>  8)
       + (int)(int8_t)(a >> 16) * (int)(int8_t)(b >> 16)
       + (int)(int8_t)(a >> 24) * (int)(int8_t)(b >> 24);
}

// ---------------- mean(|W|) for the 4 weight matrices (double accum) ----------------
__global__ __launch_bounds__(256) void wabs_sum_kernel(
    const float* __restrict__ W0, const float* __restrict__ W1,
    const float* __restrict__ W2, const float* __restrict__ W3,
    double* __restrict__ wsum)
{
  const int w   = blockIdx.x >> 6;   // 0..3
  const int blk = blockIdx.x & 63;
  const float* W = (w == 0) ? W0 : (w == 1) ? W1 : (w == 2) ? W2 : W3;
  const int n = C_ * C_;
  double s = 0.0;
  for (int i = blk * 256 + (int)threadIdx.x; i < n; i += 64 * 256)
    s += (double)fabsf(W[i]);
  __shared__ double sm[256];
  sm[threadIdx.x] = s;
  __syncthreads();
  for (int o = 128; o > 0; o >>= 1) {
    if ((int)threadIdx.x < o) sm[threadIdx.x] += sm[threadIdx.x + o];
    __syncthreads();
  }
  if (threadIdx.x == 0) atomicAdd(&wsum[w], sm[0]);
}

// ---------------- ternary weight quant: t = clip(rint(W/s),-1,1) ----------------
__global__ __launch_bounds__(256) void wquant_kernel(
    const float* __restrict__ W0, const float* __restrict__ W1,
    const float* __restrict__ W2, const float* __restrict__ W3,
    const double* __restrict__ wsum, int8_t* __restrict__ Wt, float* __restrict__ sw)
{
  const int w = blockIdx.x >> 10;    // 1024 blocks per matrix
  const float* W = (w == 0) ? W0 : (w == 1) ? W1 : (w == 2) ? W2 : W3;
  const int n = C_ * C_;
  const float s = fmaxf((float)(wsum[w] * (1.0 / (double)n)), EPSF);
  int8_t* dst = Wt + (size_t)w * n;
  const int base = (blockIdx.x & 1023) * 256 + (int)threadIdx.x;
  for (int i = base; i < n; i += 1024 * 256) {
    float t = rintf(W[i] / s);
    t = fminf(fmaxf(t, -1.f), 1.f);
    dst[i] = (int8_t)t;
  }
  if (base == 0) sw[w] = s;
}

// ---------------- per-token act_quant of x -> int8 + dequant scale ----------------
__global__ __launch_bounds__(256) void xquant_kernel(
    const float* __restrict__ x, int8_t* __restrict__ xq, float* __restrict__ sx)
{
  const int r = blockIdx.x;
  const float* xr = x + (size_t)r * C_;
  float am = 0.f;
  for (int j = threadIdx.x; j < C_; j += 256) am = fmaxf(am, fabsf(xr[j]));
  __shared__ float sm[256];
  sm[threadIdx.x] = am;
  __syncthreads();
  for (int o = 128; o > 0; o >>= 1) {
    if ((int)threadIdx.x < o) sm[threadIdx.x] = fmaxf(sm[threadIdx.x], sm[threadIdx.x + o]);
    __syncthreads();
  }
  const float m = fmaxf(sm[0], EPSF);
  const float scale = 127.f / m;
  for (int j = threadIdx.x; j < C_; j += 256) {
    float q = fminf(fmaxf(rintf(xr[j] * scale), -128.f), 127.f);
    xq[(size_t)r * C_ + j] = (int8_t)q;
  }
  if (threadIdx.x == 0) sx[r] = m / 127.f;
}

// ---------------- q/k/v projection: int8 x ternary, fused per-head act_quant ----------------
// grid (H, R/64, 3). Block tile 64 rows x 128 cols (one head). Integer-exact:
// quant is round(127*N/max|N|) -- no fp32 matmul rounding at all.
__global__ __launch_bounds__(256) void proj_gemm_kernel(
    const int8_t* __restrict__ xq, const float* __restrict__ sx,
    const int8_t* __restrict__ Wt, const float* __restrict__ sw4,
    int8_t* __restrict__ qkv, float* __restrict__ sqkv)
{
  const int h    = blockIdx.x;
  const int r0   = blockIdx.y * 64;
  const int wsel = blockIdx.z;
  const int tid  = (int)threadIdx.x;
  const int8_t* Wm = Wt + (size_t)wsel * C_ * C_;

  __shared__ uint32_t As[64][17];    // [row][kword], padded
  __shared__ uint32_t Bs[16][128];   // [kword][col]
  __shared__ int rmaxs[64];

  int acc[8][4] = {};
  const int rg = tid >> 5;           // rows rg, rg+8, ..., rg+56
  const int cg = tid & 31;           // cols cg, cg+32, cg+64, cg+96

  for (int k0 = 0; k0 < C_; k0 += 64) {
    {
      int row = tid >> 2, seg = tid & 3;
      const uint4* src = (const uint4*)(xq + (size_t)(r0 + row) * C_ + k0 + seg * 16);
      uint4 v = *src;
      As[row][seg * 4 + 0] = v.x; As[row][seg * 4 + 1] = v.y;
      As[row][seg * 4 + 2] = v.z; As[row][seg * 4 + 3] = v.w;
    }
    {
      int col = tid >> 1, half = tid & 1;
      const uint4* src = (const uint4*)(Wm + (size_t)(h * 128 + col) * C_ + k0 + half * 32);
      uint4 v0 = src[0], v1 = src[1];
      int kb = half * 8;
      Bs[kb + 0][col] = v0.x; Bs[kb + 1][col] = v0.y; Bs[kb + 2][col] = v0.z; Bs[kb + 3][col] = v0.w;
      Bs[kb + 4][col] = v1.x; Bs[kb + 5][col] = v1.y; Bs[kb + 6][col] = v1.z; Bs[kb + 7][col] = v1.w;
    }
    __syncthreads();
    for (int kw = 0; kw < 16; ++kw) {
      uint32_t bw[4];
      #pragma unroll
      for (int j = 0; j < 4; ++j) bw[j] = Bs[kw][cg + 32 * j];
      #pragma unroll
      for (int i = 0; i < 8; ++i) {
        uint32_t aw = As[rg + 8 * i][kw];
        #pragma unroll
        for (int j = 0; j < 4; ++j) acc[i][j] += dot4i8(aw, bw[j]);
      }
    }
    __syncthreads();
  }

  if (tid < 64) rmaxs[tid] = 0;
  __syncthreads();
  #pragma unroll
  for (int i = 0; i < 8; ++i) {
    int m = 0;
    #pragma unroll
    for (int j = 0; j < 4; ++j) m = max(m, abs(acc[i][j]));
    atomicMax(&rmaxs[rg + 8 * i], m);
  }
  __syncthreads();

  const float swv = sw4[wsel];
  #pragma unroll
  for (int i = 0; i < 8; ++i) {
    const int r = rg + 8 * i;
    const int rglob = r0 + r;
    const int mN = rmaxs[r];
    const float qscale = (mN > 0) ? 127.f / (float)mN : 0.f;
    const int bb = rglob >> 11;          // / T_
    const int tt = rglob & (T_ - 1);
    const size_t obase = ((size_t)(bb * H_ + h) * T_ + tt) * D_;
    #pragma unroll
    for (int j = 0; j < 4; ++j) {
      float q = rintf((float)acc[i][j] * qscale);
      q = fminf(fmaxf(q, -128.f), 127.f);
      qkv[(size_t)wsel * R_ * C_ + obase + cg + 32 * j] = (int8_t)q;
    }
    if (cg == 0) {
      float maxq = (float)mN * sx[rglob] * swv;
      sqkv[(size_t)wsel * R_ * H_ + (size_t)(bb * H_ + h) * T_ + tt] = fmaxf(maxq, EPSF) / 127.f;
    }
  }
}

// ---------------- fused attention: two-pass flash with exact w-quant ----------------
// grid (B*H, T/64). m_w = rint(127*exp(s - smax)) -- softmax denominator cancels in
// the quant, so no score materialization. y = (1/(127*Z)) * sum m_w * v, then
// per-(head,token) act_quant fused into the epilogue.
__global__ __launch_bounds__(256) void attn_kernel(
    const int8_t* __restrict__ qq, const int8_t* __restrict__ kq,
    const int8_t* __restrict__ vq, const float* __restrict__ sq,
    const float* __restrict__ sk,  const float* __restrict__ sv,
    int8_t* __restrict__ yq, float* __restrict__ sy)
{
  const int bh  = blockIdx.x;
  const int t0  = blockIdx.y * 64;
  const int b   = bh >> 4;
  const int h   = bh & 15;
  const int tid = (int)threadIdx.x;
  const int rg  = tid >> 4;   // rows 4rg..4rg+3
  const int lg  = tid & 15;   // keys 4lg..4lg+3 (QK) / dims 8lg..8lg+7 (PV)

  __shared__ uint32_t Qs[64][33];
  __shared__ uint32_t Ks[64][33];
  __shared__ uint32_t Vs[64][33];
  __shared__ float    Ws[64][65];
  __shared__ float    sqs[64], sks[64], svs[64];

  {
    int row = tid >> 2, seg = tid & 3;
    const uint4* src = (const uint4*)(qq + ((size_t)bh * T_ + (t0 + row)) * D_ + seg * 32);
    uint4 v0 = src[0], v1 = src[1];
    int wb = seg * 8;
    Qs[row][wb+0]=v0.x; Qs[row][wb+1]=v0.y; Qs[row][wb+2]=v0.z; Qs[row][wb+3]=v0.w;
    Qs[row][wb+4]=v1.x; Qs[row][wb+5]=v1.y; Qs[row][wb+6]=v1.z; Qs[row][wb+7]=v1.w;
  }
  if (tid < 64) sqs[tid] = sq[(size_t)bh * T_ + t0 + tid];
  __syncthreads();

  float sqr[4];
  #pragma unroll
  for (int i = 0; i < 4; ++i) sqr[i] = sqs[4 * rg + i] * INV_SQRT_D;

  // ---- pass 1: row max of scores ----
  float rmax[4] = {-1e30f, -1e30f, -1e30f, -1e30f};
  for (int s0 = 0; s0 < T_; s0 += 64) {
    {
      int row = tid >> 2, seg = tid & 3;
      const uint4* src = (const uint4*)(kq + ((size_t)bh * T_ + (s0 + row)) * D_ + seg * 32);
      uint4 v0 = src[0], v1 = src[1];
      int wb = seg * 8;
      Ks[row][wb+0]=v0.x; Ks[row][wb+1]=v0.y; Ks[row][wb+2]=v0.z; Ks[row][wb+3]=v0.w;
      Ks[row][wb+4]=v1.x; Ks[row][wb+5]=v1.y; Ks[row][wb+6]=v1.z; Ks[row][wb+7]=v1.w;
    }
    if (tid < 64) sks[tid] = sk[(size_t)bh * T_ + s0 + tid];
    __syncthreads();
    int acc[4][4] = {};
    for (int kw = 0; kw < 32; ++kw) {
      uint32_t aw[4], bw[4];
      #pragma unroll
      for (int i = 0; i < 4; ++i) aw[i] = Qs[4 * rg + i][kw];
      #pragma unroll
      for (int j = 0; j < 4; ++j) bw[j] = Ks[4 * lg + j][kw];
      #pragma unroll
      for (int i = 0; i < 4; ++i)
        #pragma unroll
        for (int j = 0; j < 4; ++j) acc[i][j] += dot4i8(aw[i], bw[j]);
    }
    #pragma unroll
    for (int i = 0; i < 4; ++i)
      #pragma unroll
      for (int j = 0; j < 4; ++j) {
        float sval = (float)acc[i][j] * (sqr[i] * sks[4 * lg + j]);
        rmax[i] = fmaxf(rmax[i], sval);
      }
    __syncthreads();
  }
  for (int m = 1; m < 16; m <<= 1)
    #pragma unroll
    for (int i = 0; i < 4; ++i) rmax[i] = fmaxf(rmax[i], __shfl_xor(rmax[i], m, 64));

  // ---- pass 2: quantized softmax + PV ----
  float zacc[4] = {0.f, 0.f, 0.f, 0.f};
  float yacc[4][8] = {};
  for (int s0 = 0; s0 < T_; s0 += 64) {
    {
      int row = tid >> 2, seg = tid & 3;
      const uint4* srck = (const uint4*)(kq + ((size_t)bh * T_ + (s0 + row)) * D_ + seg * 32);
      uint4 v0 = srck[0], v1 = srck[1];
      int wb = seg * 8;
      Ks[row][wb+0]=v0.x; Ks[row][wb+1]=v0.y; Ks[row][wb+2]=v0.z; Ks[row][wb+3]=v0.w;
      Ks[row][wb+4]=v1.x; Ks[row][wb+5]=v1.y; Ks[row][wb+6]=v1.z; Ks[row][wb+7]=v1.w;
      const uint4* srcv = (const uint4*)(vq + ((size_t)bh * T_ + (s0 + row)) * D_ + seg * 32);
      uint4 u0 = srcv[0], u1 = srcv[1];
      Vs[row][wb+0]=u0.x; Vs[row][wb+1]=u0.y; Vs[row][wb+2]=u0.z; Vs[row][wb+3]=u0.w;
      Vs[row][wb+4]=u1.x; Vs[row][wb+5]=u1.y; Vs[row][wb+6]=u1.z; Vs[row][wb+7]=u1.w;
    }
    if (tid < 64) {
      sks[tid] = sk[(size_t)bh * T_ + s0 + tid];
      svs[tid] = sv[(size_t)bh * T_ + s0 + tid];
    }
    __syncthreads();
    int acc[4][4] = {};
    for (int kw = 0; kw < 32; ++kw) {
      uint32_t aw[4], bw[4];
      #pragma unroll
      for (int i = 0; i < 4; ++i) aw[i] = Qs[4 * rg + i][kw];
      #pragma unroll
      for (int j = 0; j < 4; ++j) bw[j] = Ks[4 * lg + j][kw];
      #pragma unroll
      for (int i = 0; i < 4; ++i)
        #pragma unroll
        for (int j = 0; j < 4; ++j) acc[i][j] += dot4i8(aw[i], bw[j]);
    }
    #pragma unroll
    for (int i = 0; i < 4; ++i)
      #pragma unroll
      for (int j = 0; j < 4; ++j) {
        float sval = (float)acc[i][j] * (sqr[i] * sks[4 * lg + j]);
        float e = expf(sval - rmax[i]);
        zacc[i] += e;
        Ws[4 * rg + i][4 * lg + j] = rintf(127.f * e);
      }
    __syncthreads();
    // PV: thread = (rows 4rg+i, dims 8lg..8lg+7)
    for (int s = 0; s < 64; ++s) {
      const float sc = svs[s];
      const uint32_t w0 = Vs[s][2 * lg], w1 = Vs[s][2 * lg + 1];
      float v[8];
      v[0] = (float)(int)(int8_t)(w0      ) * sc;
      v[1] = (float)(int)(int8_t)(w0 >>  8) * sc;
      v[2] = (float)(int)(int8_t)(w0 >> 16) * sc;
      v[3] = (float)(int)(int8_t)(w0 >> 24) * sc;
      v[4] = (float)(int)(int8_t)(w1      ) * sc;
      v[5] = (float)(int)(int8_t)(w1 >>  8) * sc;
      v[6] = (float)(int)(int8_t)(w1 >> 16) * sc;
      v[7] = (float)(int)(int8_t)(w1 >> 24) * sc;
      #pragma unroll
      for (int i = 0; i < 4; ++i) {
        const float wv = Ws[4 * rg + i][s];
        #pragma unroll
        for (int d = 0; d < 8; ++d) yacc[i][d] += wv * v[d];
      }
    }
    __syncthreads();
  }
  for (int m = 1; m < 16; m <<= 1)
    #pragma unroll
    for (int i = 0; i < 4; ++i) zacc[i] += __shfl_xor(zacc[i], m, 64);

  // ---- epilogue: y = acc/(127*Z), per-(token,head) act_quant ----
  #pragma unroll
  for (int i = 0; i < 4; ++i) {
    const float invz = 1.f / (127.f * zacc[i]);
    float yv[8];
    float ym = 0.f;
    #pragma unroll
    for (int d = 0; d < 8; ++d) {
      yv[d] = yacc[i][d] * invz;
      ym = fmaxf(ym, fabsf(yv[d]));
    }
    for (int m = 1; m < 16; m <<= 1) ym = fmaxf(ym, __shfl_xor(ym, m, 64));
    const float fs = 127.f / fmaxf(ym, EPSF);
    const size_t rowbase = ((size_t)(b * T_ + t0 + 4 * rg + i)) * C_ + h * D_ + 8 * lg;
    #pragma unroll
    for (int d = 0; d < 8; ++d) {
      float qv = fminf(fmaxf(rintf(yv[d] * fs), -128.f), 127.f);
      yq[rowbase + d] = (int8_t)qv;
    }
    if (lg == 0)
      sy[(size_t)(b * T_ + t0 + 4 * rg + i) * H_ + h] = fmaxf(ym, EPSF) / 127.f;
  }
}

// ---------------- output projection: int8 (per-64-chunk scale) x ternary ----------------
// grid (C/128, R/64). Per 64-wide K chunk the y-scale is uniform (chunk lies inside
// one head), so accumulate int32 per chunk then fold sy[row][head] in fp32.
__global__ __launch_bounds__(256) void out_gemm_kernel(
    const int8_t* __restrict__ yq, const float* __restrict__ sy,
    const int8_t* __restrict__ Wt, const float* __restrict__ sw4,
    float* __restrict__ outp)
{
  const int n0  = blockIdx.x * 128;
  const int r0  = blockIdx.y * 64;
  const int tid = (int)threadIdx.x;
  const int8_t* Wm = Wt + (size_t)3 * C_ * C_;

  __shared__ uint32_t As[64][17];
  __shared__ uint32_t Bs[16][128];
  __shared__ float sYs[64][16];

  for (int t = tid; t < 64 * 16; t += 256)
    sYs[t >> 4][t & 15] = sy[(size_t)(r0 + (t >> 4)) * H_ + (t & 15)];

  float accF[8][4] = {};
  const int rg = tid >> 5;
  const int cg = tid & 31;

  for (int k0 = 0; k0 < C_; k0 += 64) {
    {
      int row = tid >> 2, seg = tid & 3;
      const uint4* src = (const uint4*)(yq + (size_t)(r0 + row) * C_ + k0 + seg * 16);
      uint4 v = *src;
      As[row][seg * 4 + 0] = v.x; As[row][seg * 4 + 1] = v.y;
      As[row][seg * 4 + 2] = v.z; As[row][seg * 4 + 3] = v.w;
    }
    {
      int col = tid >> 1, half = tid & 1;
      const uint4* src = (const uint4*)(Wm + (size_t)(n0 + col) * C_ + k0 + half * 32);
      uint4 v0 = src[0], v1 = src[1];
      int kb = half * 8;
      Bs[kb + 0][col] = v0.x; Bs[kb + 1][col] = v0.y; Bs[kb + 2][col] = v0.z; Bs[kb + 3][col] = v0.w;
      Bs[kb + 4][col] = v1.x; Bs[kb + 5][col] = v1.y; Bs[kb + 6][col] = v1.z; Bs[kb + 7][col] = v1.w;
    }
    __syncthreads();
    int accI[8][4] = {};
    for (int kw = 0; kw < 16; ++kw) {
      uint32_t bw[4];
      #pragma unroll
      for (int j = 0; j < 4; ++j) bw[j] = Bs[kw][cg + 32 * j];
      #pragma unroll
      for (int i = 0; i < 8; ++i) {
        uint32_t aw = As[rg + 8 * i][kw];
        #pragma unroll
        for (int j = 0; j < 4; ++j) accI[i][j] += dot4i8(aw, bw[j]);
      }
    }
    __syncthreads();
    const int hc = k0 >> 7;
    #pragma unroll
    for (int i = 0; i < 8; ++i) {
      const float s = sYs[rg + 8 * i][hc];
      #pragma unroll
      for (int j = 0; j < 4; ++j) accF[i][j] += (float)accI[i][j] * s;
    }
  }
  const float swp = sw4[3];
  #pragma unroll
  for (int i = 0; i < 8; ++i)
    #pragma unroll
    for (int j = 0; j < 4; ++j)
      outp[(size_t)(r0 + rg + 8 * i) * C_ + n0 + cg + 32 * j] = accF[i][j] * swp;
}

// ---------------- final per-token act_quant (dequantized fp32 out) ----------------
__global__ __launch_bounds__(256) void final_quant_kernel(
    const float* __restrict__ outp, float* __restrict__ out)
{
  const int r = blockIdx.x;
  const float* xr = outp + (size_t)r * C_;
  float am = 0.f;
  for (int j = threadIdx.x; j < C_; j += 256) am = fmaxf(am, fabsf(xr[j]));
  __shared__ float sm[256];
  sm[threadIdx.x] = am;
  __syncthreads();
  for (int o = 128; o > 0; o >>= 1) {
    if ((int)threadIdx.x < o) sm[threadIdx.x] = fmaxf(sm[threadIdx.x], sm[threadIdx.x + o]);
    __syncthreads();
  }
  const float m = fmaxf(sm[0], EPSF);
  const float scale = 127.f / m;
  const float inv = m / 127.f;
  for (int j = threadIdx.x; j < C_; j += 256) {
    float q = fminf(fmaxf(rintf(xr[j] * scale), -128.f), 127.f);
    out[(size_t)r * C_ + j] = q * inv;
  }
}

} // namespace

extern "C" void kernel_launch(void* const* d_in, const int* in_sizes, int n_in,
                              void* d_out, int out_size, void* d_ws, size_t ws_size,
                              hipStream_t stream)
{
  (void)in_sizes; (void)n_in; (void)out_size; (void)ws_size;
  const float* x  = (const float*)d_in[0];
  const float* W0 = (const float*)d_in[1];
  const float* W1 = (const float*)d_in[2];
  const float* W2 = (const float*)d_in[3];
  const float* W3 = (const float*)d_in[4];

  char* ws = (char*)d_ws;
  double* wsum = (double*)(ws + OFF_WSUM);
  float*  swv  = (float*) (ws + OFF_SW);
  int8_t* Wt   = (int8_t*)(ws + OFF_WT);
  int8_t* xq   = (int8_t*)(ws + OFF_XQ);
  float*  sx   = (float*) (ws + OFF_SX);
  int8_t* qkv  = (int8_t*)(ws + OFF_QKV);
  float*  sqkv = (float*) (ws + OFF_SQKV);
  int8_t* yqp  = (int8_t*)(ws + OFF_YQ);
  float*  syp  = (float*) (ws + OFF_SY);
  float*  outp = (float*) (ws + OFF_OUTP);

  hipMemsetAsync(d_ws, 0, 256, stream);
  hipLaunchKernelGGL(wabs_sum_kernel, dim3(256), dim3(256), 0, stream, W0, W1, W2, W3, wsum);
  hipLaunchKernelGGL(wquant_kernel, dim3(4096), dim3(256), 0, stream, W0, W1, W2, W3, wsum, Wt, swv);
  hipLaunchKernelGGL(xquant_kernel, dim3(R_), dim3(256), 0, stream, x, xq, sx);
  hipLaunchKernelGGL(proj_gemm_kernel, dim3(H_, R_ / 64, 3), dim3(256), 0, stream,
                     xq, sx, Wt, swv, qkv, sqkv);
  hipLaunchKernelGGL(attn_kernel, dim3(B_ * H_, T_ / 64), dim3(256), 0, stream,
                     qkv, qkv + (size_t)R_ * C_, qkv + (size_t)2 * R_ * C_,
                     sqkv, sqkv + (size_t)R_ * H_, sqkv + (size_t)2 * R_ * H_,
                     yqp, syp);
  hipLaunchKernelGGL(out_gemm_kernel, dim3(C_ / 128, R_ / 64), dim3(256), 0, stream,
                     yqp, syp, Wt, swv, outp);
  hipLaunchKernelGGL(final_quant_kernel, dim3(R_), dim3(256), 0, stream, outp, (float*)d_out);
}

// Round 2
// 638.831 us; speedup vs baseline: 6.5596x; 6.5596x over previous
//
#include <hip/hip_runtime.h>
#include <stdint.h>

namespace {

constexpr int B_ = 2, T_ = 2048, C_ = 2048, H_ = 16, D_ = 128;
constexpr int R_ = B_ * T_;                 // 4096 token rows (b*T + t)
constexpr float EPSF = 1e-5f;
constexpr float INV_SQRT_D = 0.08838834764831845f;   // 1/sqrt(128)

// ---- workspace layout (bytes) ----
constexpr size_t OFF_WSUM = 0;                                   // double[4]
constexpr size_t OFF_SW   = 64;                                  // float[4]
constexpr size_t OFF_WT   = 256;                                 // int8[4][C*C] ternary
constexpr size_t OFF_XQ   = OFF_WT   + (size_t)4 * C_ * C_;      // int8[R*C]
constexpr size_t OFF_SX   = OFF_XQ   + (size_t)R_ * C_;          // float[R]
constexpr size_t OFF_QKV  = OFF_SX   + (size_t)R_ * 4;           // int8[3][B*H*T*D]
constexpr size_t OFF_SQKV = OFF_QKV  + (size_t)3 * R_ * C_;      // float[3][B*H*T]
constexpr size_t OFF_YQ   = OFF_SQKV + (size_t)3 * R_ * H_ * 4;  // int8[R*C]
constexpr size_t OFF_SY   = OFF_YQ   + (size_t)R_ * C_;          // float[R*H]
constexpr size_t OFF_OUTP = OFF_SY   + (size_t)R_ * H_ * 4;      // float[R*C]
// vT (bf16 [bh][d][t], 16.78 MB) aliases OUTP (33.5 MB): vT is dead before
// out_gemm writes outp (stream-ordered), so no extra workspace needed.
constexpr size_t OFF_VT   = OFF_OUTP;

typedef int   i32x4 __attribute__((ext_vector_type(4)));
typedef short s16x8 __attribute__((ext_vector_type(8)));
typedef float f32x4 __attribute__((ext_vector_type(4)));

__device__ __forceinline__ i32x4 mfma_i8(i32x4 a, i32x4 b, i32x4 c) {
  return __builtin_amdgcn_mfma_i32_16x16x64_i8(a, b, c, 0, 0, 0);
}
__device__ __forceinline__ f32x4 mfma_bf16(s16x8 a, s16x8 b, f32x4 c) {
  return __builtin_amdgcn_mfma_f32_16x16x32_bf16(a, b, c, 0, 0, 0);
}

// RTNE float->bf16 bits (exact for ints |v|<=256, matches numpy RTNE)
__device__ __forceinline__ short f2bf(float f) {
  union { float f; uint32_t u; } v; v.f = f;
  uint32_t r = v.u + 0x7fffu + ((v.u >> 16) & 1u);
  return (short)(r >> 16);
}
__device__ __forceinline__ float bf2f(short h) {
  union { uint32_t u; float f; } v; v.u = ((uint32_t)(uint16_t)h) << 16;
  return v.f;
}

// ---------------- mean(|W|) for the 4 weight matrices (double accum) ----------------
__global__ __launch_bounds__(256) void wabs_sum_kernel(
    const float* __restrict__ W0, const float* __restrict__ W1,
    const float* __restrict__ W2, const float* __restrict__ W3,
    double* __restrict__ wsum)
{
  const int w   = blockIdx.x >> 6;
  const int blk = blockIdx.x & 63;
  const float* W = (w == 0) ? W0 : (w == 1) ? W1 : (w == 2) ? W2 : W3;
  const int n = C_ * C_;
  double s = 0.0;
  for (int i = blk * 256 + (int)threadIdx.x; i < n; i += 64 * 256)
    s += (double)fabsf(W[i]);
  __shared__ double sm[256];
  sm[threadIdx.x] = s;
  __syncthreads();
  for (int o = 128; o > 0; o >>= 1) {
    if ((int)threadIdx.x < o) sm[threadIdx.x] += sm[threadIdx.x + o];
    __syncthreads();
  }
  if (threadIdx.x == 0) atomicAdd(&wsum[w], sm[0]);
}

// ---------------- ternary weight quant ----------------
__global__ __launch_bounds__(256) void wquant_kernel(
    const float* __restrict__ W0, const float* __restrict__ W1,
    const float* __restrict__ W2, const float* __restrict__ W3,
    const double* __restrict__ wsum, int8_t* __restrict__ Wt, float* __restrict__ sw)
{
  const int w = blockIdx.x >> 10;
  const float* W = (w == 0) ? W0 : (w == 1) ? W1 : (w == 2) ? W2 : W3;
  const int n = C_ * C_;
  const float s = fmaxf((float)(wsum[w] * (1.0 / (double)n)), EPSF);
  int8_t* dst = Wt + (size_t)w * n;
  const int base = (blockIdx.x & 1023) * 256 + (int)threadIdx.x;
  for (int i = base; i < n; i += 1024 * 256) {
    float t = rintf(W[i] / s);
    t = fminf(fmaxf(t, -1.f), 1.f);
    dst[i] = (int8_t)t;
  }
  if (base == 0) sw[w] = s;
}

// ---------------- per-token act_quant of x ----------------
__global__ __launch_bounds__(256) void xquant_kernel(
    const float* __restrict__ x, int8_t* __restrict__ xq, float* __restrict__ sx)
{
  const int r = blockIdx.x;
  const float* xr = x + (size_t)r * C_;
  float am = 0.f;
  for (int j = threadIdx.x; j < C_; j += 256) am = fmaxf(am, fabsf(xr[j]));
  __shared__ float sm[256];
  sm[threadIdx.x] = am;
  __syncthreads();
  for (int o = 128; o > 0; o >>= 1) {
    if ((int)threadIdx.x < o) sm[threadIdx.x] = fmaxf(sm[threadIdx.x], sm[threadIdx.x + o]);
    __syncthreads();
  }
  const float m = fmaxf(sm[0], EPSF);
  const float scale = 127.f / m;
  for (int j = threadIdx.x; j < C_; j += 256) {
    float q = fminf(fmaxf(rintf(xr[j] * scale), -128.f), 127.f);
    xq[(size_t)r * C_ + j] = (int8_t)q;
  }
  if (threadIdx.x == 0) sx[r] = m / 127.f;
}

// ---------------- q/k/v projection via i8 MFMA, fused per-head act_quant ----------------
// grid (16 heads, R/128, 3). Block tile 128 rows x 128 cols (one head).
// Wave (of 4): rh=w>>1 row-half, ch=w&1 col-half -> 64x64 per wave = 4x4 MFMA tiles.
__global__ __launch_bounds__(256) void proj_mfma_kernel(
    const int8_t* __restrict__ xq, const float* __restrict__ sx,
    const int8_t* __restrict__ Wt, const float* __restrict__ sw4,
    int8_t* __restrict__ qkv, float* __restrict__ sqkv)
{
  const int h    = blockIdx.x;
  const int r0   = blockIdx.y * 128;
  const int wsel = blockIdx.z;
  const int tid  = (int)threadIdx.x;
  const int wv   = tid >> 6;
  const int lane = tid & 63;
  const int quad = lane >> 4;
  const int l15  = lane & 15;
  const int rh   = wv >> 1, ch = wv & 1;
  const int8_t* Wm = Wt + (size_t)wsel * C_ * C_;

  __shared__ __align__(16) char As[128 * 80];   // [row][64B data + 16 pad]
  __shared__ __align__(16) char Bs[128 * 80];   // [outcol][64B data + 16 pad]
  __shared__ int rmaxs[128];
  if (tid < 128) rmaxs[tid] = 0;

  i32x4 acc[4][4];
  #pragma unroll
  for (int i = 0; i < 4; ++i)
    #pragma unroll
    for (int j = 0; j < 4; ++j) acc[i][j] = i32x4{0, 0, 0, 0};

  for (int k0 = 0; k0 < C_; k0 += 64) {
    #pragma unroll
    for (int it = 0; it < 2; ++it) {
      int idx = tid + it * 256;          // 512: row = idx>>2, seg = idx&3
      int row = idx >> 2, seg = idx & 3;
      *(uint4*)(As + row * 80 + seg * 16) =
          *(const uint4*)(xq + (size_t)(r0 + row) * C_ + k0 + seg * 16);
      *(uint4*)(Bs + row * 80 + seg * 16) =
          *(const uint4*)(Wm + (size_t)(h * 128 + row) * C_ + k0 + seg * 16);
    }
    __syncthreads();
    i32x4 a[4], b[4];
    #pragma unroll
    for (int rt = 0; rt < 4; ++rt)
      a[rt] = *(const i32x4*)(As + (rh * 64 + rt * 16 + l15) * 80 + quad * 16);
    #pragma unroll
    for (int ct = 0; ct < 4; ++ct)
      b[ct] = *(const i32x4*)(Bs + (ch * 64 + ct * 16 + l15) * 80 + quad * 16);
    #pragma unroll
    for (int rt = 0; rt < 4; ++rt)
      #pragma unroll
      for (int ct = 0; ct < 4; ++ct)
        acc[rt][ct] = mfma_i8(a[rt], b[ct], acc[rt][ct]);
    __syncthreads();
  }

  // per-row abs-max over the full head (both col-half waves) via LDS atomicMax
  #pragma unroll
  for (int rt = 0; rt < 4; ++rt)
    #pragma unroll
    for (int r = 0; r < 4; ++r) {
      int m = 0;
      #pragma unroll
      for (int ct = 0; ct < 4; ++ct) {
        int v = acc[rt][ct][r];
        int av = v < 0 ? -v : v;
        m = m > av ? m : av;
      }
      #pragma unroll
      for (int mm = 1; mm < 16; mm <<= 1) {
        int o = __shfl_xor(m, mm, 64);
        m = m > o ? m : o;
      }
      if (l15 == 0) atomicMax(&rmaxs[rh * 64 + rt * 16 + quad * 4 + r], m);
    }
  __syncthreads();

  const float swv = sw4[wsel];
  #pragma unroll
  for (int rt = 0; rt < 4; ++rt)
    #pragma unroll
    for (int r = 0; r < 4; ++r) {
      const int rowl = rh * 64 + rt * 16 + quad * 4 + r;
      const int rglob = r0 + rowl;
      const int mN = rmaxs[rowl];
      const float qscale = (mN > 0) ? 127.f / (float)mN : 0.f;
      const int bb = rglob >> 11;
      const int tt = rglob & (T_ - 1);
      const size_t obase = ((size_t)(bb * H_ + h) * T_ + tt) * D_;
      #pragma unroll
      for (int ct = 0; ct < 4; ++ct) {
        const int col = ch * 64 + ct * 16 + l15;
        float q = rintf((float)acc[rt][ct][r] * qscale);
        q = fminf(fmaxf(q, -128.f), 127.f);
        qkv[(size_t)wsel * R_ * C_ + obase + col] = (int8_t)q;
      }
      if (ch == 0 && l15 == 0) {
        float maxq = (float)mN * sx[rglob] * swv;
        sqkv[(size_t)wsel * R_ * H_ + (size_t)(bb * H_ + h) * T_ + tt] =
            fmaxf(maxq, EPSF) / 127.f;
      }
    }
}

// ---------------- V transpose: int8 [bh][t][d] -> bf16 [bh][d][t] (exact) ----------------
__global__ __launch_bounds__(256) void vtrans_kernel(
    const int8_t* __restrict__ vq, short* __restrict__ vT)
{
  const int bh = blockIdx.y;
  const int s0 = blockIdx.x * 64;
  const int tid = (int)threadIdx.x;
  __shared__ __align__(16) int8_t Vs[64][144];   // 128B data + pad
  const int8_t* vbase = vq + ((size_t)bh * T_ + s0) * D_;
  #pragma unroll
  for (int it = 0; it < 2; ++it) {
    int idx = tid + it * 256;
    int row = idx >> 3, seg = idx & 7;
    *(uint4*)(&Vs[row][seg * 16]) = *(const uint4*)(vbase + row * 128 + seg * 16);
  }
  __syncthreads();
  const int d = tid >> 1;
  const int kh = (tid & 1) * 32;
  uint32_t out[16];
  #pragma unroll
  for (int i = 0; i < 32; i += 2) {
    short b0 = f2bf((float)(int)Vs[kh + i][d]);
    short b1 = f2bf((float)(int)Vs[kh + i + 1][d]);
    out[i >> 1] = (uint32_t)(uint16_t)b0 | ((uint32_t)(uint16_t)b1 << 16);
  }
  short* dst = vT + ((size_t)bh * D_ + d) * T_ + s0 + kh;
  #pragma unroll
  for (int i = 0; i < 4; ++i) {
    uint4 o;
    o.x = out[4 * i + 0]; o.y = out[4 * i + 1];
    o.z = out[4 * i + 2]; o.w = out[4 * i + 3];
    *(uint4*)(dst + 8 * i) = o;
  }
}

// ---------------- fused attention: two-pass flash, i8-MFMA QK + bf16-MFMA PV ----------------
// grid (B*H, T/64). 4 waves; wave w owns Q rows 16w..16w+15.
// QK exact int32; w = rint(127*exp(s-rmax)) exact; PV: A = (w*sv) split hi/lo bf16,
// B = raw int8 v exact in bf16 -> ~2^-17 accurate.
__global__ __launch_bounds__(256) void attn_mfma_kernel(
    const int8_t* __restrict__ qq, const int8_t* __restrict__ kq,
    const float* __restrict__ sq, const float* __restrict__ sk,
    const float* __restrict__ sv, const short* __restrict__ vT,
    int8_t* __restrict__ yq, float* __restrict__ sy)
{
  const int bh  = blockIdx.x;
  const int t0  = blockIdx.y * 64;
  const int tid = (int)threadIdx.x;
  const int w   = tid >> 6;
  const int lane = tid & 63;
  const int quad = lane >> 4;
  const int l15  = lane & 15;

  __shared__ __align__(16) char smem[46848];
  char* Ks = smem;                 // [64 keys][144] int8 (128B data)
  char* Wh = smem + 9216;          // [64 rows][144] bf16 (64 keys) ; Q staging overlay
  char* Wl = smem + 18432;         // [64 rows][144] bf16
  char* VT = smem + 27648;         // [128 dims][144] bf16 (64 keys)
  float* sqs = (float*)(smem + 46080);
  float* sks = (float*)(smem + 46336);
  float* svs = (float*)(smem + 46592);

  // ---- stage Q (overlay on Wh), pull A-frags to regs ----
  {
    const int8_t* qbase = qq + ((size_t)bh * T_ + t0) * D_;
    #pragma unroll
    for (int it = 0; it < 2; ++it) {
      int idx = tid + it * 256;
      int row = idx >> 3, seg = idx & 7;
      *(uint4*)(Wh + row * 144 + seg * 16) = *(const uint4*)(qbase + row * 128 + seg * 16);
    }
    if (tid < 64) sqs[tid] = sq[(size_t)bh * T_ + t0 + tid];
  }
  __syncthreads();
  i32x4 aq0, aq1;
  {
    const int row = 16 * w + l15;
    aq0 = *(const i32x4*)(Wh + row * 144 + quad * 16);
    aq1 = *(const i32x4*)(Wh + row * 144 + 64 + quad * 16);
  }
  float sqr[4];
  #pragma unroll
  for (int r = 0; r < 4; ++r) sqr[r] = sqs[16 * w + quad * 4 + r] * INV_SQRT_D;
  __syncthreads();

  // ---- pass 1: exact row max of scores ----
  float rmax[4] = {-3e38f, -3e38f, -3e38f, -3e38f};
  for (int s0 = 0; s0 < T_; s0 += 64) {
    const int8_t* kbase = kq + ((size_t)bh * T_ + s0) * D_;
    #pragma unroll
    for (int it = 0; it < 2; ++it) {
      int idx = tid + it * 256;
      int row = idx >> 3, seg = idx & 7;
      *(uint4*)(Ks + row * 144 + seg * 16) = *(const uint4*)(kbase + row * 128 + seg * 16);
    }
    if (tid < 64) sks[tid] = sk[(size_t)bh * T_ + s0 + tid];
    __syncthreads();
    #pragma unroll
    for (int kt = 0; kt < 4; ++kt) {
      const int key = kt * 16 + l15;
      i32x4 b0 = *(const i32x4*)(Ks + key * 144 + quad * 16);
      i32x4 b1 = *(const i32x4*)(Ks + key * 144 + 64 + quad * 16);
      i32x4 c = i32x4{0, 0, 0, 0};
      c = mfma_i8(aq0, b0, c);
      c = mfma_i8(aq1, b1, c);
      const float skc = sks[key];
      #pragma unroll
      for (int r = 0; r < 4; ++r) {
        float sval = (float)c[r] * (sqr[r] * skc);
        rmax[r] = fmaxf(rmax[r], sval);
      }
    }
    __syncthreads();
  }
  #pragma unroll
  for (int mm = 1; mm < 16; mm <<= 1)
    #pragma unroll
    for (int r = 0; r < 4; ++r) rmax[r] = fmaxf(rmax[r], __shfl_xor(rmax[r], mm, 64));

  // ---- pass 2: quantized softmax + PV ----
  float zacc[4] = {0.f, 0.f, 0.f, 0.f};
  f32x4 yacc[8];
  #pragma unroll
  for (int dt = 0; dt < 8; ++dt) yacc[dt] = f32x4{0.f, 0.f, 0.f, 0.f};

  short* WhS = (short*)Wh;   // stride 72 shorts/row
  short* WlS = (short*)Wl;

  for (int s0 = 0; s0 < T_; s0 += 64) {
    {
      const int8_t* kbase = kq + ((size_t)bh * T_ + s0) * D_;
      #pragma unroll
      for (int it = 0; it < 2; ++it) {
        int idx = tid + it * 256;
        int row = idx >> 3, seg = idx & 7;
        *(uint4*)(Ks + row * 144 + seg * 16) = *(const uint4*)(kbase + row * 128 + seg * 16);
      }
      const short* vtb = vT + (size_t)bh * D_ * T_ + s0;
      #pragma unroll
      for (int it = 0; it < 4; ++it) {
        int idx = tid + it * 256;            // 1024: d = idx>>3, seg = idx&7
        int d = idx >> 3, seg = idx & 7;
        *(uint4*)(VT + d * 144 + seg * 16) =
            *(const uint4*)((const char*)(vtb + (size_t)d * T_) + seg * 16);
      }
      if (tid < 64) {
        sks[tid] = sk[(size_t)bh * T_ + s0 + tid];
        svs[tid] = sv[(size_t)bh * T_ + s0 + tid];
      }
    }
    __syncthreads();
    // QK + softmax + W hi/lo write (wave-private rows)
    #pragma unroll
    for (int kt = 0; kt < 4; ++kt) {
      const int key = kt * 16 + l15;
      i32x4 b0 = *(const i32x4*)(Ks + key * 144 + quad * 16);
      i32x4 b1 = *(const i32x4*)(Ks + key * 144 + 64 + quad * 16);
      i32x4 c = i32x4{0, 0, 0, 0};
      c = mfma_i8(aq0, b0, c);
      c = mfma_i8(aq1, b1, c);
      const float skc = sks[key];
      const float svc = svs[key];
      #pragma unroll
      for (int r = 0; r < 4; ++r) {
        float sval = (float)c[r] * (sqr[r] * skc);
        float e = expf(sval - rmax[r]);
        zacc[r] += e;
        float wf = rintf(127.f * e) * svc;
        short hb = f2bf(wf);
        short lb = f2bf(wf - bf2f(hb));
        const int rowl = 16 * w + quad * 4 + r;
        WhS[rowl * 72 + key] = hb;
        WlS[rowl * 72 + key] = lb;
      }
    }
    __threadfence_block();   // wave-private W rows: lgkmcnt drain, no block barrier
    // PV
    #pragma unroll
    for (int kc = 0; kc < 2; ++kc) {
      s16x8 ah = *(const s16x8*)(Wh + (16 * w + l15) * 144 + kc * 64 + quad * 16);
      s16x8 al = *(const s16x8*)(Wl + (16 * w + l15) * 144 + kc * 64 + quad * 16);
      #pragma unroll
      for (int dt = 0; dt < 8; ++dt) {
        s16x8 vb = *(const s16x8*)(VT + (dt * 16 + l15) * 144 + kc * 64 + quad * 16);
        yacc[dt] = mfma_bf16(ah, vb, yacc[dt]);
        yacc[dt] = mfma_bf16(al, vb, yacc[dt]);
      }
    }
    __syncthreads();
  }
  #pragma unroll
  for (int mm = 1; mm < 16; mm <<= 1)
    #pragma unroll
    for (int r = 0; r < 4; ++r) zacc[r] += __shfl_xor(zacc[r], mm, 64);

  // ---- epilogue: y = yacc/(127 Z), per-(token,head) act_quant ----
  const int b = bh >> 4;
  const int h = bh & 15;
  #pragma unroll
  for (int r = 0; r < 4; ++r) {
    float ym = 0.f;
    #pragma unroll
    for (int dt = 0; dt < 8; ++dt) ym = fmaxf(ym, fabsf(yacc[dt][r]));
    #pragma unroll
    for (int mm = 1; mm < 16; mm <<= 1) ym = fmaxf(ym, __shfl_xor(ym, mm, 64));
    const float invz = 1.f / (127.f * zacc[r]);
    const float ymt = fmaxf(ym * invz, EPSF);
    const float fs = 127.f / ymt;
    const int tglob = t0 + 16 * w + quad * 4 + r;
    const size_t rowbase = ((size_t)(b * T_ + tglob)) * C_ + h * D_;
    #pragma unroll
    for (int dt = 0; dt < 8; ++dt) {
      float yv = yacc[dt][r] * invz;
      float qv = fminf(fmaxf(rintf(yv * fs), -128.f), 127.f);
      yq[rowbase + dt * 16 + l15] = (int8_t)qv;
    }
    if (l15 == 0)
      sy[(size_t)(b * T_ + tglob) * H_ + h] = ymt / 127.f;
  }
}

// ---------------- output projection: i8 MFMA, per-head (K=128) scale folding ----------------
// grid (C/64, R/128). Wave tile 64 rows x 32 cols (4x2 tiles); int32 acc per head,
// folded into fp32 with sy[row][head] every 2 K-chunks.
__global__ __launch_bounds__(256) void outproj_mfma_kernel(
    const int8_t* __restrict__ yq, const float* __restrict__ sy,
    const int8_t* __restrict__ Wt, const float* __restrict__ sw4,
    float* __restrict__ outp)
{
  const int n0  = blockIdx.x * 64;
  const int r0  = blockIdx.y * 128;
  const int tid = (int)threadIdx.x;
  const int wv   = tid >> 6;
  const int lane = tid & 63;
  const int quad = lane >> 4;
  const int l15  = lane & 15;
  const int rh   = wv >> 1, ch = wv & 1;
  const int8_t* Wm = Wt + (size_t)3 * C_ * C_;

  __shared__ __align__(16) char As[128 * 80];
  __shared__ __align__(16) char Bs[64 * 80];
  __shared__ float sYs[128][16];
  for (int idx = tid; idx < 128 * 16; idx += 256)
    sYs[idx >> 4][idx & 15] = sy[(size_t)(r0 + (idx >> 4)) * H_ + (idx & 15)];

  i32x4 iacc[4][2];
  f32x4 facc[4][2];
  #pragma unroll
  for (int i = 0; i < 4; ++i)
    #pragma unroll
    for (int j = 0; j < 2; ++j) { iacc[i][j] = i32x4{0,0,0,0}; facc[i][j] = f32x4{0.f,0.f,0.f,0.f}; }

  for (int kc = 0; kc < 32; ++kc) {
    const int k0 = kc * 64;
    #pragma unroll
    for (int it = 0; it < 2; ++it) {
      int idx = tid + it * 256;
      int row = idx >> 2, seg = idx & 3;
      *(uint4*)(As + row * 80 + seg * 16) =
          *(const uint4*)(yq + (size_t)(r0 + row) * C_ + k0 + seg * 16);
    }
    {
      int col = tid >> 2, seg = tid & 3;
      *(uint4*)(Bs + col * 80 + seg * 16) =
          *(const uint4*)(Wm + (size_t)(n0 + col) * C_ + k0 + seg * 16);
    }
    __syncthreads();
    i32x4 a[4], b[2];
    #pragma unroll
    for (int rt = 0; rt < 4; ++rt)
      a[rt] = *(const i32x4*)(As + (rh * 64 + rt * 16 + l15) * 80 + quad * 16);
    #pragma unroll
    for (int ct = 0; ct < 2; ++ct)
      b[ct] = *(const i32x4*)(Bs + (ch * 32 + ct * 16 + l15) * 80 + quad * 16);
    #pragma unroll
    for (int rt = 0; rt < 4; ++rt)
      #pragma unroll
      for (int ct = 0; ct < 2; ++ct)
        iacc[rt][ct] = mfma_i8(a[rt], b[ct], iacc[rt][ct]);
    __syncthreads();
    if (kc & 1) {
      const int hd = kc >> 1;
      #pragma unroll
      for (int rt = 0; rt < 4; ++rt)
        #pragma unroll
        for (int r = 0; r < 4; ++r) {
          const float s = sYs[rh * 64 + rt * 16 + quad * 4 + r][hd];
          #pragma unroll
          for (int ct = 0; ct < 2; ++ct)
            facc[rt][ct][r] += (float)iacc[rt][ct][r] * s;
        }
      #pragma unroll
      for (int rt = 0; rt < 4; ++rt)
        #pragma unroll
        for (int ct = 0; ct < 2; ++ct) iacc[rt][ct] = i32x4{0,0,0,0};
    }
  }
  const float swp = sw4[3];
  #pragma unroll
  for (int rt = 0; rt < 4; ++rt)
    #pragma unroll
    for (int r = 0; r < 4; ++r) {
      const int rowl = rh * 64 + rt * 16 + quad * 4 + r;
      #pragma unroll
      for (int ct = 0; ct < 2; ++ct)
        outp[(size_t)(r0 + rowl) * C_ + n0 + ch * 32 + ct * 16 + l15] =
            facc[rt][ct][r] * swp;
    }
}

// ---------------- final per-token act_quant ----------------
__global__ __launch_bounds__(256) void final_quant_kernel(
    const float* __restrict__ outp, float* __restrict__ out)
{
  const int r = blockIdx.x;
  const float* xr = outp + (size_t)r * C_;
  float am = 0.f;
  for (int j = threadIdx.x; j < C_; j += 256) am = fmaxf(am, fabsf(xr[j]));
  __shared__ float sm[256];
  sm[threadIdx.x] = am;
  __syncthreads();
  for (int o = 128; o > 0; o >>= 1) {
    if ((int)threadIdx.x < o) sm[threadIdx.x] = fmaxf(sm[threadIdx.x], sm[threadIdx.x + o]);
    __syncthreads();
  }
  const float m = fmaxf(sm[0], EPSF);
  const float scale = 127.f / m;
  const float inv = m / 127.f;
  for (int j = threadIdx.x; j < C_; j += 256) {
    float q = fminf(fmaxf(rintf(xr[j] * scale), -128.f), 127.f);
    out[(size_t)r * C_ + j] = q * inv;
  }
}

} // namespace

extern "C" void kernel_launch(void* const* d_in, const int* in_sizes, int n_in,
                              void* d_out, int out_size, void* d_ws, size_t ws_size,
                              hipStream_t stream)
{
  (void)in_sizes; (void)n_in; (void)out_size; (void)ws_size;
  const float* x  = (const float*)d_in[0];
  const float* W0 = (const float*)d_in[1];
  const float* W1 = (const float*)d_in[2];
  const float* W2 = (const float*)d_in[3];
  const float* W3 = (const float*)d_in[4];

  char* ws = (char*)d_ws;
  double* wsum = (double*)(ws + OFF_WSUM);
  float*  swv  = (float*) (ws + OFF_SW);
  int8_t* Wt   = (int8_t*)(ws + OFF_WT);
  int8_t* xq   = (int8_t*)(ws + OFF_XQ);
  float*  sx   = (float*) (ws + OFF_SX);
  int8_t* qkv  = (int8_t*)(ws + OFF_QKV);
  float*  sqkv = (float*) (ws + OFF_SQKV);
  int8_t* yqp  = (int8_t*)(ws + OFF_YQ);
  float*  syp  = (float*) (ws + OFF_SY);
  float*  outp = (float*) (ws + OFF_OUTP);
  short*  vT   = (short*) (ws + OFF_VT);     // aliases outp (see layout note)

  hipMemsetAsync(d_ws, 0, 256, stream);
  hipLaunchKernelGGL(wabs_sum_kernel, dim3(256), dim3(256), 0, stream, W0, W1, W2, W3, wsum);
  hipLaunchKernelGGL(wquant_kernel, dim3(4096), dim3(256), 0, stream, W0, W1, W2, W3, wsum, Wt, swv);
  hipLaunchKernelGGL(xquant_kernel, dim3(R_), dim3(256), 0, stream, x, xq, sx);
  hipLaunchKernelGGL(proj_mfma_kernel, dim3(H_, R_ / 128, 3), dim3(256), 0, stream,
                     xq, sx, Wt, swv, qkv, sqkv);
  hipLaunchKernelGGL(vtrans_kernel, dim3(T_ / 64, B_ * H_), dim3(256), 0, stream,
                     qkv + (size_t)2 * R_ * C_, vT);
  hipLaunchKernelGGL(attn_mfma_kernel, dim3(B_ * H_, T_ / 64), dim3(256), 0, stream,
                     qkv, qkv + (size_t)R_ * C_,
                     sqkv, sqkv + (size_t)R_ * H_, sqkv + (size_t)2 * R_ * H_,
                     vT, yqp, syp);
  hipLaunchKernelGGL(outproj_mfma_kernel, dim3(C_ / 64, R_ / 128), dim3(256), 0, stream,
                     yqp, syp, Wt, swv, outp);
  hipLaunchKernelGGL(final_quant_kernel, dim3(R_), dim3(256), 0, stream, outp, (float*)d_out);
}